// Round 13
// baseline (39.661 us; speedup 1.0000x reference)
//
#include <hip/hip_runtime.h>
#include <hip/hip_bf16.h>

// Problem constants (from reference)
#define BB   16
#define VV   5
#define NPTS 8192
#define CCH  128
#define HH   41
#define WW   32
#define HWS  (HH * WW)      // 1312
#define BVN  (BB * VV)      // 80
#define OUTC (3 + CCH)      // 131
#define PPB  64             // points per block in gather (R13: 16 -> 64)

#define NSCAT BVN                                // 80 scatter blocks (1 per bv)
#define NTRAN ((HWS / 32) * (CCH / 32) * BVN)    // 41*4*80 = 13120 transpose blocks

typedef unsigned int u32;

static __device__ __forceinline__ ushort f2bf(float x) {
    __hip_bfloat16 h = __float2bfloat16(x);      // RNE
    return *reinterpret_cast<ushort*>(&h);
}
static __device__ __forceinline__ float bf2f(ushort u) {
    return __uint_as_float(((u32)u) << 16);
}

// ---------------------------------------------------------------------------
// Kernel 1 (unchanged from R12): scatter + transpose, XCD-pinned by batch.
//  blocks [0, 80): winner resolution in LDS. numpy fancy-assignment = last
//    i wins; key = (i<<11)|src (24 bits), init -1.
//  blocks [80, 80+13120): 32x32 transpose tile, float4 in / ushort4 out,
//    feat (BV,C,HW) f32 -> feat_t (BV,HW,C) bf16 (threshold 0.104 >> bf16
//    err ~0.01 on N(0,1)).
//  Lessons: R7 non-temporal regress; R9 row-split regress; R10 big-tile
//  regress; R11 K2-pinning -4.2 us; R12 producer-pinning neutral (K1's own
//  streaming evicts feat_t before K2 reads it).
// ---------------------------------------------------------------------------
__global__ void scatter_and_transpose(const int* __restrict__ i3, const int* __restrict__ i2,
                                      int* __restrict__ win,
                                      const float* __restrict__ feat,
                                      __hip_bfloat16* __restrict__ feat_t) {
    __shared__ int smem[NPTS];                   // 32 KB, aliased by transpose tile
    int tid = threadIdx.x;                       // 256
    int n   = blockIdx.x;

    if (n < NSCAT) {
        int xcd = n & 7, s = n >> 3;             // s in [0,10)
        int bv  = (xcd + 8 * (s / 5)) * 5 + (s % 5);
        const int* p3 = i3 + (size_t)bv * (NPTS + 1);
        const int* p2 = i2 + (size_t)bv * (NPTS + 1);
        for (int j = tid; j < NPTS; j += 256) smem[j] = -1;
        __syncthreads();
        int cnt = p3[0];
        for (int i = tid; i < cnt; i += 256) {
            int tgt = p3[1 + i];                 // [0, NPTS)
            int src = p2[1 + i];                 // [0, HWS)
            atomicMax(&smem[tgt], (i << 11) | src);
        }
        __syncthreads();
        int4* wg = (int4*)(win + (size_t)bv * NPTS);
        const int4* s4 = (const int4*)smem;
        for (int j = tid; j < NPTS / 4; j += 256) wg[j] = s4[j];
        return;
    }

    // ---- transpose block, batch-pinned ----
    float (*tile)[37] = (float (*)[37])smem;
    int m   = n - NSCAT;                         // [0,13120), m%8 == n%8
    int xcd = m & 7, s = m >> 3;                 // s in [0,1640)
    int b   = xcd + 8 * (s / 820);
    int w   = s % 820;
    int bv  = b * 5 + w / 164;
    int rem = w % 164;
    int hw0 = (rem % 41) * 32;
    int c0  = (rem / 41) * 32;
    const float*    inp  = feat   + (size_t)bv * CCH * HWS;
    __hip_bfloat16* outp = feat_t + (size_t)bv * HWS * CCH;

    {   // read: ty = c row (0..31), tx = hw quad (0..7), float4 along hw
        int ty = tid >> 3, tx = tid & 7;
        float4 v = *(const float4*)(inp + (size_t)(c0 + ty) * HWS + hw0 + 4 * tx);
        tile[ty][4 * tx + 0] = v.x;
        tile[ty][4 * tx + 1] = v.y;
        tile[ty][4 * tx + 2] = v.z;
        tile[ty][4 * tx + 3] = v.w;
    }
    __syncthreads();
    {   // write: h = hw (0..31), q = c quad (0..7), ushort4 (4 bf16 = 8B)
        int h = tid >> 3, q = tid & 7;
        ushort4 v;
        v.x = f2bf(tile[4 * q + 0][h]);
        v.y = f2bf(tile[4 * q + 1][h]);
        v.z = f2bf(tile[4 * q + 2][h]);
        v.w = f2bf(tile[4 * q + 3][h]);
        *(ushort4*)((ushort*)outp + (size_t)(hw0 + h) * CCH + c0 + 4 * q) = v;
    }
}

// ---------------------------------------------------------------------------
// Kernel 2 (R13: PPB 16 -> 64, 1024 threads): per point, max over views
// (unset view contributes exact 0.0; NOT a clamp). 16B uint4 per view per
// lane (full 256B coalesced row-segment per (point,view) across 16 lanes),
// 5 independent loads in flight. Output rows staged in LDS; one contiguous
// 33.5 KB coalesced block write (was 8.4 KB) for DRAM page sequentiality.
// XCD-pinning: xcd=n&7, slot=n>>3 (0..255), b=xcd+8*(slot>>7), j=slot&127.
// ---------------------------------------------------------------------------
__global__ __launch_bounds__(1024) void gather_out_bf(
        const float* __restrict__ pc, const ushort* __restrict__ feat_t,
        const int* __restrict__ win, float* __restrict__ out) {
    __shared__ __align__(16) float srow[PPB * OUTC];   // 64*131 = 8384 floats, 33.5 KB
    int tid  = threadIdx.x;         // 1024
    int row  = tid >> 4;            // 0..63
    int c8   = tid & 15;            // 8-channel group index

    int n    = blockIdx.x;          // 0..2047
    int xcd  = n & 7;
    int slot = n >> 3;              // 0..255
    int b    = xcd + 8 * (slot >> 7);
    int j    = slot & 127;
    int bp0  = (b * 128 + j) * PPB; // batch-local block j, 64 points
    int bp   = bp0 + row;
    int p    = (bp & (NPTS - 1));

    int keys[VV];
#pragma unroll
    for (int v = 0; v < VV; ++v)
        keys[v] = win[(b * VV + v) * NPTS + p];

    float acc[8];
#pragma unroll
    for (int j2 = 0; j2 < 8; ++j2) acc[j2] = -INFINITY;

#pragma unroll
    for (int v = 0; v < VV; ++v) {
        float val[8];
        if (keys[v] >= 0) {
            int src = keys[v] & 2047;
            uint4 q = *(const uint4*)(feat_t + (((size_t)(b * VV + v) * HWS + src) << 7) + (c8 << 3));
            val[0] = bf2f((ushort)(q.x & 0xffff)); val[1] = bf2f((ushort)(q.x >> 16));
            val[2] = bf2f((ushort)(q.y & 0xffff)); val[3] = bf2f((ushort)(q.y >> 16));
            val[4] = bf2f((ushort)(q.z & 0xffff)); val[5] = bf2f((ushort)(q.z >> 16));
            val[6] = bf2f((ushort)(q.w & 0xffff)); val[7] = bf2f((ushort)(q.w >> 16));
        } else {
#pragma unroll
            for (int j2 = 0; j2 < 8; ++j2) val[j2] = 0.0f;
        }
#pragma unroll
        for (int j2 = 0; j2 < 8; ++j2) acc[j2] = fmaxf(acc[j2], val[j2]);
    }

    float* sr = srow + row * OUTC;
#pragma unroll
    for (int j2 = 0; j2 < 8; ++j2) sr[3 + 8 * c8 + j2] = acc[j2];
    if (c8 < 3) sr[c8] = pc[(size_t)bp * 3 + c8];
    __syncthreads();

    // coalesced aligned copy-out: 8384 floats = 2096 float4, 33.5 KB contiguous
    float* obase = out + (size_t)bp0 * OUTC;
    const float4* s4 = (const float4*)srow;
    for (int i = tid; i < (PPB * OUTC) / 4; i += 1024)
        *(float4*)(obase + 4 * i) = s4[i];
}

extern "C" void kernel_launch(void* const* d_in, const int* in_sizes, int n_in,
                              void* d_out, int out_size, void* d_ws, size_t ws_size,
                              hipStream_t stream) {
    const float* pc   = (const float*)d_in[0];
    const float* feat = (const float*)d_in[1];
    const int*   i3   = (const int*)d_in[2];
    const int*   i2   = (const int*)d_in[3];
    float*       out  = (float*)d_out;

    const size_t win_bytes = (size_t)BVN * NPTS * sizeof(int);   // 2.62 MB

    int* win = (int*)d_ws;
    __hip_bfloat16* feat_t = (__hip_bfloat16*)((char*)d_ws + win_bytes);
    (void)ws_size;

    scatter_and_transpose<<<NSCAT + NTRAN, 256, 0, stream>>>(i3, i2, win, feat, feat_t);
    gather_out_bf<<<(BB * NPTS) / PPB, 1024, 0, stream>>>(pc, (const ushort*)feat_t, win, out);
}

// Round 14
// 38.771 us; speedup vs baseline: 1.0230x; 1.0230x over previous
//
#include <hip/hip_runtime.h>
#include <hip/hip_bf16.h>

// Problem constants (from reference)
#define BB   16
#define VV   5
#define NPTS 8192
#define CCH  128
#define HH   41
#define WW   32
#define HWS  (HH * WW)      // 1312
#define BVN  (BB * VV)      // 80
#define OUTC (3 + CCH)      // 131
#define PPB  16             // points per block in gather (R13's 64 regressed)

#define NSCAT BVN                                // 80 scatter blocks (1 per bv)
#define NTRAN ((HWS / 32) * (CCH / 32) * BVN)    // 41*4*80 = 13120 transpose blocks

typedef unsigned int u32;

static __device__ __forceinline__ ushort f2bf(float x) {
    __hip_bfloat16 h = __float2bfloat16(x);      // RNE
    return *reinterpret_cast<ushort*>(&h);
}
static __device__ __forceinline__ float bf2f(ushort u) {
    return __uint_as_float(((u32)u) << 16);
}

// ---------------------------------------------------------------------------
// FINAL (R14 = best-known: R12 K1 + R11 K2). Measured 38.7-39.0 us.
// Lever ledger: vectorize+LDS-stage -36; LDS-resident win -28; bf16
// intermediate -15; K2 XCD-pin -4.2 | NT hints +3.2; fused 1-pass +164;
// 128x32 tile +2.2; PPB=64 +0.7 | producer-pin 0 (kept).
// ---------------------------------------------------------------------------
// Kernel 1: scatter + transpose, XCD-pinned by batch.
//  blocks [0, 80): winner resolution in LDS. numpy fancy-assignment = last
//    i wins; key = (i<<11)|src (24 bits), init -1.
//  blocks [80, 80+13120): 32x32 transpose tile, float4 in / ushort4 out,
//    feat (BV,C,HW) f32 -> feat_t (BV,HW,C) bf16 (threshold 0.104 >> bf16
//    err ~0.01 on N(0,1) features).
// ---------------------------------------------------------------------------
__global__ void scatter_and_transpose(const int* __restrict__ i3, const int* __restrict__ i2,
                                      int* __restrict__ win,
                                      const float* __restrict__ feat,
                                      __hip_bfloat16* __restrict__ feat_t) {
    __shared__ int smem[NPTS];                   // 32 KB, aliased by transpose tile
    int tid = threadIdx.x;                       // 256
    int n   = blockIdx.x;

    if (n < NSCAT) {
        int xcd = n & 7, s = n >> 3;             // s in [0,10)
        int bv  = (xcd + 8 * (s / 5)) * 5 + (s % 5);
        const int* p3 = i3 + (size_t)bv * (NPTS + 1);
        const int* p2 = i2 + (size_t)bv * (NPTS + 1);
        for (int j = tid; j < NPTS; j += 256) smem[j] = -1;
        __syncthreads();
        int cnt = p3[0];
        for (int i = tid; i < cnt; i += 256) {
            int tgt = p3[1 + i];                 // [0, NPTS)
            int src = p2[1 + i];                 // [0, HWS)
            atomicMax(&smem[tgt], (i << 11) | src);
        }
        __syncthreads();
        int4* wg = (int4*)(win + (size_t)bv * NPTS);
        const int4* s4 = (const int4*)smem;
        for (int j = tid; j < NPTS / 4; j += 256) wg[j] = s4[j];
        return;
    }

    // ---- transpose block, batch-pinned ----
    float (*tile)[37] = (float (*)[37])smem;
    int m   = n - NSCAT;                         // [0,13120), m%8 == n%8
    int xcd = m & 7, s = m >> 3;                 // s in [0,1640)
    int b   = xcd + 8 * (s / 820);
    int w   = s % 820;
    int bv  = b * 5 + w / 164;
    int rem = w % 164;
    int hw0 = (rem % 41) * 32;
    int c0  = (rem / 41) * 32;
    const float*    inp  = feat   + (size_t)bv * CCH * HWS;
    __hip_bfloat16* outp = feat_t + (size_t)bv * HWS * CCH;

    {   // read: ty = c row (0..31), tx = hw quad (0..7), float4 along hw
        int ty = tid >> 3, tx = tid & 7;
        float4 v = *(const float4*)(inp + (size_t)(c0 + ty) * HWS + hw0 + 4 * tx);
        tile[ty][4 * tx + 0] = v.x;
        tile[ty][4 * tx + 1] = v.y;
        tile[ty][4 * tx + 2] = v.z;
        tile[ty][4 * tx + 3] = v.w;
    }
    __syncthreads();
    {   // write: h = hw (0..31), q = c quad (0..7), ushort4 (4 bf16 = 8B)
        int h = tid >> 3, q = tid & 7;
        ushort4 v;
        v.x = f2bf(tile[4 * q + 0][h]);
        v.y = f2bf(tile[4 * q + 1][h]);
        v.z = f2bf(tile[4 * q + 2][h]);
        v.w = f2bf(tile[4 * q + 3][h]);
        *(ushort4*)((ushort*)outp + (size_t)(hw0 + h) * CCH + c0 + 4 * q) = v;
    }
}

// ---------------------------------------------------------------------------
// Kernel 2: per point, max over views (unset view contributes exact 0.0; NOT
// a clamp). 16B uint4 per view per lane, 5 independent loads in flight.
// Output rows staged in LDS, contiguous coalesced 8384 B block write.
// XCD-pinning: xcd=n&7, slot=n>>3, b=xcd+8*(slot>>9), j=slot&511 -- the
// batch's 1.68 MB feat_t slice + win stay resident in the home XCD L2
// across the 5-view reuse (-4.2 us, R11).
// ---------------------------------------------------------------------------
__global__ void gather_out_bf(const float* __restrict__ pc, const ushort* __restrict__ feat_t,
                              const int* __restrict__ win, float* __restrict__ out) {
    __shared__ __align__(16) float srow[PPB * OUTC];   // 16*131 = 2096 floats
    int tid  = threadIdx.x;         // 256
    int row  = tid >> 4;            // 0..15
    int c8   = tid & 15;            // 8-channel group index

    int n    = blockIdx.x;          // 0..8191
    int xcd  = n & 7;
    int slot = n >> 3;              // 0..1023
    int b    = xcd + 8 * (slot >> 9);
    int j    = slot & 511;
    int bp0  = (b * 512 + j) * PPB; // batch-local block j, 16 points
    int bp   = bp0 + row;
    int p    = (bp & (NPTS - 1));

    int keys[VV];
#pragma unroll
    for (int v = 0; v < VV; ++v)
        keys[v] = win[(b * VV + v) * NPTS + p];

    float acc[8];
#pragma unroll
    for (int j2 = 0; j2 < 8; ++j2) acc[j2] = -INFINITY;

#pragma unroll
    for (int v = 0; v < VV; ++v) {
        float val[8];
        if (keys[v] >= 0) {
            int src = keys[v] & 2047;
            uint4 q = *(const uint4*)(feat_t + (((size_t)(b * VV + v) * HWS + src) << 7) + (c8 << 3));
            val[0] = bf2f((ushort)(q.x & 0xffff)); val[1] = bf2f((ushort)(q.x >> 16));
            val[2] = bf2f((ushort)(q.y & 0xffff)); val[3] = bf2f((ushort)(q.y >> 16));
            val[4] = bf2f((ushort)(q.z & 0xffff)); val[5] = bf2f((ushort)(q.z >> 16));
            val[6] = bf2f((ushort)(q.w & 0xffff)); val[7] = bf2f((ushort)(q.w >> 16));
        } else {
#pragma unroll
            for (int j2 = 0; j2 < 8; ++j2) val[j2] = 0.0f;
        }
#pragma unroll
        for (int j2 = 0; j2 < 8; ++j2) acc[j2] = fmaxf(acc[j2], val[j2]);
    }

    float* sr = srow + row * OUTC;
#pragma unroll
    for (int j2 = 0; j2 < 8; ++j2) sr[3 + 8 * c8 + j2] = acc[j2];
    if (c8 < 3) sr[c8] = pc[(size_t)bp * 3 + c8];
    __syncthreads();

    // coalesced aligned copy-out: 2096 floats = 524 float4
    float* obase = out + (size_t)bp0 * OUTC;
    const float4* s4 = (const float4*)srow;
    for (int i = tid; i < (PPB * OUTC) / 4; i += 256)
        *(float4*)(obase + 4 * i) = s4[i];
}

extern "C" void kernel_launch(void* const* d_in, const int* in_sizes, int n_in,
                              void* d_out, int out_size, void* d_ws, size_t ws_size,
                              hipStream_t stream) {
    const float* pc   = (const float*)d_in[0];
    const float* feat = (const float*)d_in[1];
    const int*   i3   = (const int*)d_in[2];
    const int*   i2   = (const int*)d_in[3];
    float*       out  = (float*)d_out;

    const size_t win_bytes = (size_t)BVN * NPTS * sizeof(int);   // 2.62 MB

    int* win = (int*)d_ws;
    __hip_bfloat16* feat_t = (__hip_bfloat16*)((char*)d_ws + win_bytes);
    (void)ws_size;

    scatter_and_transpose<<<NSCAT + NTRAN, 256, 0, stream>>>(i3, i2, win, feat, feat_t);
    gather_out_bf<<<(BB * NPTS) / PPB, 256, 0, stream>>>(pc, (const ushort*)feat_t, win, out);
}